// Round 1
// baseline (460.921 us; speedup 1.0000x reference)
//
#include <hip/hip_runtime.h>

// Problem constants (match reference setup_inputs)
#define Bz 2
#define Dz 160
#define Hz 192
#define Wz 160
#define HWl (Hz*Wz)           // 30720
#define DHWl (Dz*Hz*Wz)       // 4915200

// LNCC tiling
#define TH 16
#define TW 32
#define DT 32
#define RAWH (TH+8)           // 24
#define RAWW (TW+8)           // 40
#define NB_H (Hz/TH)          // 12
#define NB_W (Wz/TW)          // 5
#define NB_D (Dz/DT)          // 5
#define LNCC_BLOCKS (Bz*NB_H*NB_W*NB_D)  // 600
#define LNCC_THREADS 512

// Flow gradient
#define FLOW_N4 ((Bz*3*Dz*Hz*Wz)/4)     // 7372800 float4s

// Fused LNCC: per block, walk D with a 9-slice rolling window held per-thread.
// ws[0] accumulates sum of cc over all voxels (double).
__global__ __launch_bounds__(LNCC_THREADS, 2)
void lncc_kernel(const float* __restrict__ F, const float* __restrict__ M,
                 double* __restrict__ ws) {
    __shared__ float2 raw[RAWH][RAWW];     // (f, m) raw slice tile, zero-padded halo
    __shared__ float4 wbv[RAWH][TW];       // W-boxed: (Sf, Sm, Sff, Smm)
    __shared__ float  wbs[RAWH][TW];       // W-boxed: Sfm
    __shared__ double wred[LNCC_THREADS/64];

    const int bid = blockIdx.x;
    const int dc = bid % NB_D;
    const int wc = (bid / NB_D) % NB_W;
    const int hc = (bid / (NB_D * NB_W)) % NB_H;
    const int b  = bid / (NB_D * NB_W * NB_H);

    const int tid = threadIdx.x;
    const int th = tid >> 5;       // 0..15
    const int tw = tid & 31;       // 0..31

    const int h0 = hc * TH;
    const int w0 = wc * TW;
    const int d0 = dc * DT;
    const size_t bbase = (size_t)b * DHWl;

    // 9-slice circular buffer of H-boxed window values, per thread
    float circ[9][5];
#pragma unroll
    for (int i = 0; i < 9; ++i)
#pragma unroll
        for (int j = 0; j < 5; ++j) circ[i][j] = 0.f;
    float rs0 = 0.f, rs1 = 0.f, rs2 = 0.f, rs3 = 0.f, rs4 = 0.f;
    float cc_acc = 0.f;

    for (int s = d0 - 4; s <= d0 + DT + 3; ++s) {
        float nv0 = 0.f, nv1 = 0.f, nv2 = 0.f, nv3 = 0.f, nv4 = 0.f;
        if (s >= 0 && s < Dz) {            // block-uniform branch
            __syncthreads();               // protect previous iteration's LDS reads
            // ---- stage raw slice (zero outside volume) ----
            const size_t sbase = bbase + (size_t)s * HWl;
            for (int i = tid; i < RAWH * RAWW; i += LNCC_THREADS) {
                const int r = i / RAWW;
                const int c = i - r * RAWW;
                const int gh = h0 - 4 + r;
                const int gw = w0 - 4 + c;
                float fv = 0.f, mv = 0.f;
                if (gh >= 0 && gh < Hz && gw >= 0 && gw < Wz) {
                    const size_t gi = sbase + (size_t)gh * Wz + gw;
                    fv = F[gi];
                    mv = M[gi];
                }
                raw[r][c] = make_float2(fv, mv);
            }
            __syncthreads();
            // ---- W-box: 9-tap sums of the 5 products ----
            for (int i = tid; i < RAWH * TW; i += LNCC_THREADS) {
                const int r = i >> 5;
                const int j = i & 31;
                float sf = 0.f, sm = 0.f, sff = 0.f, smm = 0.f, sfm = 0.f;
#pragma unroll
                for (int t = 0; t < 9; ++t) {
                    const float2 fm = raw[r][j + t];
                    sf  += fm.x;
                    sm  += fm.y;
                    sff += fm.x * fm.x;
                    smm += fm.y * fm.y;
                    sfm += fm.x * fm.y;
                }
                wbv[r][j] = make_float4(sf, sm, sff, smm);
                wbs[r][j] = sfm;
            }
            __syncthreads();
            // ---- H-box: 9 taps over W-boxed rows ----
#pragma unroll
            for (int t = 0; t < 9; ++t) {
                const float4 v = wbv[th + t][tw];
                nv0 += v.x; nv1 += v.y; nv2 += v.z; nv3 += v.w;
                nv4 += wbs[th + t][tw];
            }
        }
        // ---- rolling D update: slot(s) == slot(s-9) ----
        int slot = s % 9; if (slot < 0) slot += 9;
        rs0 += nv0 - circ[slot][0]; circ[slot][0] = nv0;
        rs1 += nv1 - circ[slot][1]; circ[slot][1] = nv1;
        rs2 += nv2 - circ[slot][2]; circ[slot][2] = nv2;
        rs3 += nv3 - circ[slot][3]; circ[slot][3] = nv3;
        rs4 += nv4 - circ[slot][4]; circ[slot][4] = nv4;
        if (s >= d0 + 4) {                 // out_d = s - 4 in [d0, d0+DT)
            const float inv_n = 1.0f / 729.0f;
            const float mf   = rs0 * inv_n;
            const float mm   = rs1 * inv_n;
            const float varf = rs2 - mf * mf;
            const float varm = rs3 - mm * mm;
            const float cov  = rs4 - mf * mm;
            const float cc = cov * cov / (varf * varm + 1e-8f);
            cc_acc += cc;
        }
    }

    // ---- reduce cc_acc over block, then one double atomic ----
    double v = (double)cc_acc;
#pragma unroll
    for (int off = 32; off > 0; off >>= 1) v += __shfl_down(v, off);
    const int wave = tid >> 6, lane = tid & 63;
    if (lane == 0) wred[wave] = v;
    __syncthreads();
    if (tid == 0) {
        double t = 0.0;
        for (int i = 0; i < LNCC_THREADS / 64; ++i) t += wred[i];
        atomicAdd(&ws[0], t);
    }
}

// Flow gradient: backward diffs along D (ws[1]), H (ws[2]), W (ws[3]).
__global__ __launch_bounds__(256)
void flow_grad_kernel(const float* __restrict__ X, double* __restrict__ ws) {
    __shared__ double wr0[4], wr1[4], wr2[4];
    float sd = 0.f, sh = 0.f, sw = 0.f;
    const int stride = gridDim.x * blockDim.x;
    for (int i4 = blockIdx.x * blockDim.x + threadIdx.x; i4 < FLOW_N4; i4 += stride) {
        const int base = i4 * 4;                     // < 2^31, safe
        const float4 v = *(const float4*)(X + base);
        const int pos  = base % DHWl;                // position within (b,c) volume
        const int w    = pos % Wz;
        const int rest = pos / Wz;
        const int h    = rest % Hz;
        const int d    = rest / Hz;
        // W diffs (within-row; W divisible by 4 so float4 never crosses a row)
        float s = fabsf(v.y - v.x) + fabsf(v.z - v.y) + fabsf(v.w - v.z);
        if (w > 0) s += fabsf(v.x - X[base - 1]);
        sw += s;
        if (h > 0) {
            const float4 u = *(const float4*)(X + base - Wz);
            sh += fabsf(v.x - u.x) + fabsf(v.y - u.y) + fabsf(v.z - u.z) + fabsf(v.w - u.w);
        }
        if (d > 0) {
            const float4 u = *(const float4*)(X + base - HWl);
            sd += fabsf(v.x - u.x) + fabsf(v.y - u.y) + fabsf(v.z - u.z) + fabsf(v.w - u.w);
        }
    }
    double a = (double)sd, b = (double)sh, c = (double)sw;
#pragma unroll
    for (int off = 32; off > 0; off >>= 1) {
        a += __shfl_down(a, off);
        b += __shfl_down(b, off);
        c += __shfl_down(c, off);
    }
    const int wave = threadIdx.x >> 6, lane = threadIdx.x & 63;
    if (lane == 0) { wr0[wave] = a; wr1[wave] = b; wr2[wave] = c; }
    __syncthreads();
    if (threadIdx.x == 0) {
        double ta = 0.0, tb = 0.0, tc = 0.0;
        for (int i = 0; i < 4; ++i) { ta += wr0[i]; tb += wr1[i]; tc += wr2[i]; }
        atomicAdd(&ws[1], ta);   // D-diff sum (reference "dy")
        atomicAdd(&ws[2], tb);   // H-diff sum (reference "dx")
        atomicAdd(&ws[3], tc);   // W-diff sum (reference "dz")
    }
}

__global__ void finalize_kernel(const double* __restrict__ ws, float* __restrict__ out) {
    if (threadIdx.x == 0 && blockIdx.x == 0) {
        const double n_cc = 9830400.0;           // 2*1*160*192*160
        const double n_dx = 29337600.0;          // 2*3*160*191*160 (H diffs)
        const double n_dy = 29306880.0;          // 2*3*159*192*160 (D diffs)
        const double n_dz = 29306880.0;          // 2*3*160*192*159 (W diffs)
        const double L_sim = -ws[0] / n_cc;
        const double L_reg = ws[2] / n_dx + ws[1] / n_dy + ws[3] / n_dz;
        out[0] = (float)(L_sim + L_reg);
        out[1] = (float)L_sim;
        out[2] = (float)L_reg;
    }
}

extern "C" void kernel_launch(void* const* d_in, const int* in_sizes, int n_in,
                              void* d_out, int out_size, void* d_ws, size_t ws_size,
                              hipStream_t stream) {
    (void)in_sizes; (void)n_in; (void)out_size; (void)ws_size;
    const float* F = (const float*)d_in[0];   // I_fixed
    const float* M = (const float*)d_in[1];   // I_moved
    const float* X = (const float*)d_in[2];   // flow
    double* ws = (double*)d_ws;
    float* out = (float*)d_out;

    hipMemsetAsync(d_ws, 0, 4 * sizeof(double), stream);
    lncc_kernel<<<LNCC_BLOCKS, LNCC_THREADS, 0, stream>>>(F, M, ws);
    flow_grad_kernel<<<2048, 256, 0, stream>>>(X, ws);
    finalize_kernel<<<1, 64, 0, stream>>>(ws, out);
}

// Round 3
// 375.248 us; speedup vs baseline: 1.2283x; 1.2283x over previous
//
#include <hip/hip_runtime.h>

// Problem constants (match reference setup_inputs)
#define Bz 2
#define Dz 160
#define Hz 192
#define Wz 160
#define HWl (Hz*Wz)           // 30720
#define DHWl (Dz*Hz*Wz)       // 4915200

// LNCC tiling
#define TH 16
#define TW 32
#define DT 32
#define RAWH (TH+8)           // 24
#define RAWW (TW+8)           // 40
#define NB_H (Hz/TH)          // 12
#define NB_W (Wz/TW)          // 5
#define NB_D (Dz/DT)          // 5
#define LNCC_BLOCKS (Bz*NB_H*NB_W*NB_D)  // 600
#define LNCC_THREADS 512
#define NSLICE (DT+8)         // 40 D-slices walked per block

// Flow gradient
#define FLOW_BLOCKS 2048
#define FLOW_THREADS 256
#define FLOW_N4 ((Bz*3*DHWl)/4)          // 7372800 float4s

// ws layout (doubles), two-phase mode:
//   ws[0 .. 599]                      : per-block lncc cc partials
//   ws[FPO + 3*b + {0,1,2}]          : per-block flow partials (d,h,w)
// fallback (atomic) mode: ws[0]=cc, ws[1]=d, ws[2]=h, ws[3]=w
#define FPO LNCC_BLOCKS                  // 600
#define WS_DOUBLES (FPO + 3*FLOW_BLOCKS) // 6744

// Fused LNCC. mode=1: write per-block partial; mode=0: atomicAdd(ws[0]).
__global__ __launch_bounds__(LNCC_THREADS, 2)
void lncc_kernel(const float* __restrict__ F, const float* __restrict__ M,
                 double* __restrict__ ws, int mode) {
    __shared__ float2 raw[RAWH][RAWW];     // (f, m) raw slice tile, zero-padded halo
    __shared__ float4 wbv[RAWH][TW];       // W-boxed: (Sf, Sm, Sff, Smm)
    __shared__ float  wbs[RAWH][TW];       // W-boxed: Sfm
    __shared__ double wred[LNCC_THREADS/64];

    const int bid = blockIdx.x;
    const int dc = bid % NB_D;
    const int wc = (bid / NB_D) % NB_W;
    const int hc = (bid / (NB_D * NB_W)) % NB_H;
    const int b  = bid / (NB_D * NB_W * NB_H);

    const int tid = threadIdx.x;
    const int th = tid >> 5;       // 0..15
    const int tw = tid & 31;       // 0..31

    const int h0 = hc * TH;
    const int w0 = wc * TW;
    const int d0 = dc * DT;
    const size_t bbase = (size_t)b * DHWl;

    // 9-slice rolling window of H-boxed values. EVERY access below uses a
    // compile-time [q][j] index (q from the fully-unrolled inner loop), so
    // SROA keeps this in VGPRs. (Round-1 used a runtime slot -> 490 MB of
    // scratch traffic, VGPR_Count=28, WRITE_SIZE=292MB.)
    float circ[9][5];
#pragma unroll
    for (int i = 0; i < 9; ++i)
#pragma unroll
        for (int j = 0; j < 5; ++j) circ[i][j] = 0.f;
    float rs0 = 0.f, rs1 = 0.f, rs2 = 0.f, rs3 = 0.f, rs4 = 0.f;
    float cc_acc = 0.f;

    for (int i0 = 0; i0 < NSLICE; i0 += 9) {
#pragma unroll
        for (int q = 0; q < 9; ++q) {
            const int i = i0 + q;              // slice index within walk
            if (i < NSLICE) {                  // uniform guard (i0 runtime, q const)
                const int s = d0 - 4 + i;      // global D slice
                float nv0 = 0.f, nv1 = 0.f, nv2 = 0.f, nv3 = 0.f, nv4 = 0.f;
                if (s >= 0 && s < Dz) {        // block-uniform branch
                    __syncthreads();           // protect previous iteration's LDS reads
                    // ---- stage raw slice (zero outside volume) ----
                    const size_t sbase = bbase + (size_t)s * HWl;
                    for (int k = tid; k < RAWH * RAWW; k += LNCC_THREADS) {
                        const int r = k / RAWW;
                        const int c = k - r * RAWW;
                        const int gh = h0 - 4 + r;
                        const int gw = w0 - 4 + c;
                        float fv = 0.f, mv = 0.f;
                        if (gh >= 0 && gh < Hz && gw >= 0 && gw < Wz) {
                            const size_t gi = sbase + (size_t)gh * Wz + gw;
                            fv = F[gi];
                            mv = M[gi];
                        }
                        raw[r][c] = make_float2(fv, mv);
                    }
                    __syncthreads();
                    // ---- W-box: 9-tap sums of the 5 products ----
                    for (int k = tid; k < RAWH * TW; k += LNCC_THREADS) {
                        const int r = k >> 5;
                        const int j = k & 31;
                        float sf = 0.f, sm = 0.f, sff = 0.f, smm = 0.f, sfm = 0.f;
#pragma unroll
                        for (int t = 0; t < 9; ++t) {
                            const float2 fm = raw[r][j + t];
                            sf  += fm.x;
                            sm  += fm.y;
                            sff += fm.x * fm.x;
                            smm += fm.y * fm.y;
                            sfm += fm.x * fm.y;
                        }
                        wbv[r][j] = make_float4(sf, sm, sff, smm);
                        wbs[r][j] = sfm;
                    }
                    __syncthreads();
                    // ---- H-box: 9 taps over W-boxed rows ----
#pragma unroll
                    for (int t = 0; t < 9; ++t) {
                        const float4 v = wbv[th + t][tw];
                        nv0 += v.x; nv1 += v.y; nv2 += v.z; nv3 += v.w;
                        nv4 += wbs[th + t][tw];
                    }
                }
                // ---- rolling D update: compile-time slot q ----
                rs0 += nv0 - circ[q][0]; circ[q][0] = nv0;
                rs1 += nv1 - circ[q][1]; circ[q][1] = nv1;
                rs2 += nv2 - circ[q][2]; circ[q][2] = nv2;
                rs3 += nv3 - circ[q][3]; circ[q][3] = nv3;
                rs4 += nv4 - circ[q][4]; circ[q][4] = nv4;
                if (i >= 8) {                  // out_d = s - 4 in [d0, d0+DT)
                    const float inv_n = 1.0f / 729.0f;
                    const float mf   = rs0 * inv_n;
                    const float mm   = rs1 * inv_n;
                    const float varf = rs2 - mf * mf;
                    const float varm = rs3 - mm * mm;
                    const float cov  = rs4 - mf * mm;
                    const float cc = cov * cov / (varf * varm + 1e-8f);
                    cc_acc += cc;
                }
            }
        }
    }

    // ---- reduce cc_acc over block ----
    double v = (double)cc_acc;
#pragma unroll
    for (int off = 32; off > 0; off >>= 1) v += __shfl_down(v, off);
    const int wave = tid >> 6, lane = tid & 63;
    if (lane == 0) wred[wave] = v;
    __syncthreads();
    if (tid == 0) {
        double t = 0.0;
        for (int k = 0; k < LNCC_THREADS / 64; ++k) t += wred[k];
        if (mode) ws[bid] = t;                 // private slot, no contention
        else      atomicAdd(&ws[0], t);
    }
}

// Flow gradient: backward diffs along D, H, W.
__global__ __launch_bounds__(FLOW_THREADS)
void flow_grad_kernel(const float* __restrict__ X, double* __restrict__ ws, int mode) {
    __shared__ double wr0[4], wr1[4], wr2[4];
    float sd = 0.f, sh = 0.f, sw = 0.f;
    const int stride = gridDim.x * blockDim.x;
    for (int i4 = blockIdx.x * blockDim.x + threadIdx.x; i4 < FLOW_N4; i4 += stride) {
        const int base = i4 * 4;                     // < 2^31, safe
        const float4 v = *(const float4*)(X + base);
        const int pos  = base % DHWl;                // position within (b,c) volume
        const int w    = pos % Wz;
        const int rest = pos / Wz;
        const int h    = rest % Hz;
        const int d    = rest / Hz;
        // W diffs (within-row; W divisible by 4 so float4 never crosses a row)
        float s = fabsf(v.y - v.x) + fabsf(v.z - v.y) + fabsf(v.w - v.z);
        if (w > 0) s += fabsf(v.x - X[base - 1]);
        sw += s;
        if (h > 0) {
            const float4 u = *(const float4*)(X + base - Wz);
            sh += fabsf(v.x - u.x) + fabsf(v.y - u.y) + fabsf(v.z - u.z) + fabsf(v.w - u.w);
        }
        if (d > 0) {
            const float4 u = *(const float4*)(X + base - HWl);
            sd += fabsf(v.x - u.x) + fabsf(v.y - u.y) + fabsf(v.z - u.z) + fabsf(v.w - u.w);
        }
    }
    double a = (double)sd, b = (double)sh, c = (double)sw;
#pragma unroll
    for (int off = 32; off > 0; off >>= 1) {
        a += __shfl_down(a, off);
        b += __shfl_down(b, off);
        c += __shfl_down(c, off);
    }
    const int wave = threadIdx.x >> 6, lane = threadIdx.x & 63;
    if (lane == 0) { wr0[wave] = a; wr1[wave] = b; wr2[wave] = c; }
    __syncthreads();
    if (threadIdx.x == 0) {
        double ta = 0.0, tb = 0.0, tc = 0.0;
        for (int k = 0; k < 4; ++k) { ta += wr0[k]; tb += wr1[k]; tc += wr2[k]; }
        if (mode) {
            double* p = ws + FPO + 3 * (size_t)blockIdx.x;
            p[0] = ta; p[1] = tb; p[2] = tc;      // private slots
        } else {
            atomicAdd(&ws[1], ta);
            atomicAdd(&ws[2], tb);
            atomicAdd(&ws[3], tc);
        }
    }
}

__global__ __launch_bounds__(512)
void finalize_kernel(const double* __restrict__ ws, float* __restrict__ out, int mode) {
    __shared__ double red[4][8];
    double cc = 0.0, sd = 0.0, sh = 0.0, sw = 0.0;
    const int tid = threadIdx.x;
    if (mode) {
        for (int i = tid; i < LNCC_BLOCKS; i += 512) cc += ws[i];
        for (int i = tid; i < FLOW_BLOCKS; i += 512) {
            const double* p = ws + FPO + 3 * (size_t)i;
            sd += p[0]; sh += p[1]; sw += p[2];
        }
    } else if (tid == 0) {
        cc = ws[0]; sd = ws[1]; sh = ws[2]; sw = ws[3];
    }
#pragma unroll
    for (int off = 32; off > 0; off >>= 1) {
        cc += __shfl_down(cc, off);
        sd += __shfl_down(sd, off);
        sh += __shfl_down(sh, off);
        sw += __shfl_down(sw, off);
    }
    const int wave = tid >> 6, lane = tid & 63;
    if (lane == 0) { red[0][wave] = cc; red[1][wave] = sd; red[2][wave] = sh; red[3][wave] = sw; }
    __syncthreads();
    if (tid == 0) {
        double tcc = 0.0, tsd = 0.0, tsh = 0.0, tsw = 0.0;
        for (int k = 0; k < 8; ++k) {
            tcc += red[0][k]; tsd += red[1][k]; tsh += red[2][k]; tsw += red[3][k];
        }
        const double n_cc = 9830400.0;           // 2*1*160*192*160
        const double n_dx = 29337600.0;          // H diffs: 2*3*160*191*160
        const double n_dy = 29306880.0;          // D diffs: 2*3*159*192*160
        const double n_dz = 29306880.0;          // W diffs: 2*3*160*192*159
        const double L_sim = -tcc / n_cc;
        const double L_reg = tsh / n_dx + tsd / n_dy + tsw / n_dz;
        out[0] = (float)(L_sim + L_reg);
        out[1] = (float)L_sim;
        out[2] = (float)L_reg;
    }
}

extern "C" void kernel_launch(void* const* d_in, const int* in_sizes, int n_in,
                              void* d_out, int out_size, void* d_ws, size_t ws_size,
                              hipStream_t stream) {
    (void)in_sizes; (void)n_in; (void)out_size;
    const float* F = (const float*)d_in[0];   // I_fixed
    const float* M = (const float*)d_in[1];   // I_moved
    const float* X = (const float*)d_in[2];   // flow
    double* ws = (double*)d_ws;
    float* out = (float*)d_out;

    const int mode = (ws_size >= WS_DOUBLES * sizeof(double)) ? 1 : 0;
    if (!mode) hipMemsetAsync(d_ws, 0, 4 * sizeof(double), stream);

    lncc_kernel<<<LNCC_BLOCKS, LNCC_THREADS, 0, stream>>>(F, M, ws, mode);
    flow_grad_kernel<<<FLOW_BLOCKS, FLOW_THREADS, 0, stream>>>(X, ws, mode);
    finalize_kernel<<<1, 512, 0, stream>>>(ws, out, mode);
}